// Round 8
// baseline (263.524 us; speedup 1.0000x reference)
//
#include <hip/hip_runtime.h>
#include <math.h>

// SAE hierarchical, R8.
// R7 diagnosis: VALUBusy stuck at 34% -- one 16-wave barrier-locked block/CU
// exposes all L2 latency; every block redundantly converts W fp32->bf16.
// R8: (1) prep kernel converts W1/W2 to bf16 ONCE into d_ws, PRE-SWIZZLED in
// the LDS tile layout -> main staging is a pure linear uint4 copy;
// (2) 512-thread blocks (8 waves, ROWS=32, CAP=128, LDS 76.6KB) -> 2 blocks/CU,
// two independent barrier domains fill each other's stalls;
// (3) unroll-2 exact-rescue for load ILP.
// Pipeline per level: approx pre-acts via mfma_f32_16x16x32_bf16 on bf16 data
// (error ~0.03 << 0.4 threshold margin -> candidate set contains true top-k),
// sigma-threshold push to LDS + count-check retry, exact fp32 recompute of all
// candidates, exact u64-key top-k (value desc, low index tie-break), decode.

#define D64   64
#define ROWS  32
#define CAP   128
#define FTILE 256
#define HID1  4096
#define HID2  2048
#define K1    32
#define K2    16

typedef __attribute__((ext_vector_type(8))) short bf16x8;
typedef __attribute__((ext_vector_type(4))) float f32x4;

__device__ __forceinline__ unsigned short f2bf(float f) {
    unsigned u = __float_as_uint(f);
    return (unsigned short)((u + 0x7FFFu + ((u >> 16) & 1u)) >> 16);
}

__device__ __forceinline__ unsigned long long wave_max_u64(unsigned long long m) {
#pragma unroll
    for (int off = 32; off > 0; off >>= 1) {
        unsigned lo = (unsigned)m, hi = (unsigned)(m >> 32);
        unsigned olo = __shfl_xor(lo, off, 64);
        unsigned ohi = __shfl_xor(hi, off, 64);
        unsigned long long o = ((unsigned long long)ohi << 32) | (unsigned long long)olo;
        if (o > m) m = o;
    }
    return m;
}

__device__ __forceinline__ float wave_sum_f32(float v) {
#pragma unroll
    for (int off = 32; off > 0; off >>= 1) v += __shfl_xor(v, off, 64);
    return v;
}

// ---- prep: W1|W2 fp32 -> bf16, row-swizzled into LDS tile layout ----
// halfword k of row f lands at wh[f*64 + 8*((k>>3)^(f&7)) + (k&7)]
__global__ __launch_bounds__(256) void prep_w(const float* __restrict__ W1,
                                              const float* __restrict__ W2,
                                              unsigned short* __restrict__ wh) {
    const int t = blockIdx.x * 256 + threadIdx.x;   // one float4 each; 98304 total
    const int f = t >> 4, c = t & 15;
    const float* src = (f < HID1) ? (W1 + (size_t)f * D64)
                                  : (W2 + (size_t)(f - HID1) * D64);
    float4 wv = ((const float4*)src)[c];
    unsigned long long pk = (unsigned long long)f2bf(wv.x)
                         | ((unsigned long long)f2bf(wv.y) << 16)
                         | ((unsigned long long)f2bf(wv.z) << 32)
                         | ((unsigned long long)f2bf(wv.w) << 48);
    *(unsigned long long*)&wh[(size_t)f * D64 + 8 * ((c >> 1) ^ (f & 7)) + (c & 1) * 4] = pk;
}

__global__ __launch_bounds__(512) void sae_hier_mfma(
    const float* __restrict__ x,
    const float* __restrict__ W1,  const float* __restrict__ b1,
    const float* __restrict__ Wd1, const float* __restrict__ bd1,
    const float* __restrict__ W2,  const float* __restrict__ b2,
    const float* __restrict__ Wd2, const float* __restrict__ bd2,
    const unsigned short* __restrict__ wh,
    float* __restrict__ out)
{
    __shared__ uint2 s_buf[ROWS * CAP];                       // 32 KB candidates
    __shared__ __align__(16) float s_xf32[ROWS * D64];        // 8 KB exact input
    __shared__ __align__(16) unsigned short s_ah[ROWS * D64]; // 4 KB bf16 A
    __shared__ __align__(16) unsigned short s_b[FTILE * D64]; // 32 KB bf16 B tile
    __shared__ float s_sig[ROWS];
    __shared__ float s_thr[ROWS];
    __shared__ float s_scale[ROWS];
    __shared__ int   s_cnt[ROWS];
    __shared__ int   s_act[ROWS];
    __shared__ int   s_anybad;

    const int tid  = threadIdx.x;
    const int lane = tid & 63;
    const int wu   = __builtin_amdgcn_readfirstlane(tid >> 6);
    const int rowbase = blockIdx.x * ROWS;

    // ---- stage (x - b_dec): fp32 exact + bf16 swizzled + 2*sigma ----
    {
        const int r = tid >> 4, q = tid & 15;                 // 32 rows x 16 quads
        float4 a = ((const float4*)x)[(size_t)(rowbase + r) * 16 + q];
        float4 b = ((const float4*)bd1)[q];
        float4 v = make_float4(a.x - b.x, a.y - b.y, a.z - b.z, a.w - b.w);
        ((float4*)s_xf32)[r * 16 + q] = v;
        unsigned long long pk =  (unsigned long long)f2bf(v.x)
                              | ((unsigned long long)f2bf(v.y) << 16)
                              | ((unsigned long long)f2bf(v.z) << 32)
                              | ((unsigned long long)f2bf(v.w) << 48);
        *(unsigned long long*)&s_ah[r * D64 + 8 * ((q >> 1) ^ (r & 7)) + (q & 1) * 4] = pk;
        float ss = fmaf(v.x, v.x, fmaf(v.y, v.y, fmaf(v.z, v.z, v.w * v.w)));
        ss += __shfl_xor(ss, 1, 64); ss += __shfl_xor(ss, 2, 64);
        ss += __shfl_xor(ss, 4, 64); ss += __shfl_xor(ss, 8, 64);
        if (q == 0) s_sig[r] = 0.25f * sqrtf(ss);             // 2*sigma = ||.||/4
    }

    const int wr = wu & 1, wc = wu >> 1;      // 2 row groups x 4 col groups
    const int g  = lane >> 4;
    const int arow = wr * 16 + (lane & 15);

#pragma unroll 1
    for (int level = 0; level < 2; ++level) {
        const float* We  = level ? W2  : W1;
        const float* be  = level ? b2  : b1;
        const float* Wd  = level ? Wd2 : Wd1;
        const float* bdv = level ? bd2 : bd1;
        const unsigned short* whL = wh + (level ? (size_t)HID1 * D64 : 0);
        const int KSEL   = level ? K2 : K1;
        const int NPASS  = (level ? HID2 : HID1) / FTILE;

        if (tid < ROWS) { s_cnt[tid] = 0; s_scale[tid] = 1.0f; s_act[tid] = 1; }
        __syncthreads();

        // ============== approx GEMM + threshold push (with retry) ==============
#pragma unroll 1
        for (int attempt = 0; attempt < 8; ++attempt) {
            if (tid < ROWS) s_thr[tid] = s_act[tid] ? s_sig[tid] * s_scale[tid] : 3.4e38f;
            __syncthreads();
            const int rb = wr * 16 + g * 4;
            float t0 = s_thr[rb + 0], t1 = s_thr[rb + 1];
            float t2 = s_thr[rb + 2], t3 = s_thr[rb + 3];

#pragma unroll 1
            for (int p = 0; p < NPASS; ++p) {
                {   // stage B tile: linear copy of pre-swizzled bf16 (32 KB)
                    const uint4* src = (const uint4*)(whL + (size_t)p * FTILE * D64);
                    uint4* dst = (uint4*)s_b;
#pragma unroll
                    for (int i = 0; i < 4; ++i) dst[i * 512 + tid] = src[i * 512 + tid];
                }
                __syncthreads();
                {   // MFMA: wave computes 16 rows x 64 feats; push approx > thr
                    bf16x8 a0 = *(const bf16x8*)&s_ah[arow * D64 + 8 * ((0 + g) ^ (arow & 7))];
                    bf16x8 a1 = *(const bf16x8*)&s_ah[arow * D64 + 8 * ((4 + g) ^ (arow & 7))];
#pragma unroll
                    for (int sub = 0; sub < 4; ++sub) {
                        const int fl = wc * 64 + sub * 16 + (lane & 15);
                        bf16x8 b0  = *(const bf16x8*)&s_b[fl * D64 + 8 * ((0 + g) ^ (fl & 7))];
                        bf16x8 b1v = *(const bf16x8*)&s_b[fl * D64 + 8 * ((4 + g) ^ (fl & 7))];
                        f32x4 acc = {0.f, 0.f, 0.f, 0.f};
                        acc = __builtin_amdgcn_mfma_f32_16x16x32_bf16(a0, b0,  acc, 0, 0, 0);
                        acc = __builtin_amdgcn_mfma_f32_16x16x32_bf16(a1, b1v, acc, 0, 0, 0);
                        const int colg = p * FTILE + fl;
                        const float bias = be[colg];
                        float v0 = fmaxf(acc[0] + bias, 0.f);
                        float v1 = fmaxf(acc[1] + bias, 0.f);
                        float v2 = fmaxf(acc[2] + bias, 0.f);
                        float v3 = fmaxf(acc[3] + bias, 0.f);
                        const int rb2 = wr * 16 + g * 4;
                        if (v0 > t0) { int s = atomicAdd(&s_cnt[rb2 + 0], 1); if (s < CAP) s_buf[(rb2 + 0) * CAP + s] = make_uint2(__float_as_uint(v0), (unsigned)colg); }
                        if (v1 > t1) { int s = atomicAdd(&s_cnt[rb2 + 1], 1); if (s < CAP) s_buf[(rb2 + 1) * CAP + s] = make_uint2(__float_as_uint(v1), (unsigned)colg); }
                        if (v2 > t2) { int s = atomicAdd(&s_cnt[rb2 + 2], 1); if (s < CAP) s_buf[(rb2 + 2) * CAP + s] = make_uint2(__float_as_uint(v2), (unsigned)colg); }
                        if (v3 > t3) { int s = atomicAdd(&s_cnt[rb2 + 3], 1); if (s < CAP) s_buf[(rb2 + 3) * CAP + s] = make_uint2(__float_as_uint(v3), (unsigned)colg); }
                    }
                }
                __syncthreads();
            }
            if (tid == 0) s_anybad = 0;
            __syncthreads();
            if (tid < ROWS) {
                int c = s_cnt[tid];
                bool lo = (c < KSEL), hi = (c > CAP);
                bool bad = (lo || hi) && (attempt < 7);
                s_act[tid] = bad ? 1 : 0;
                if (bad) { s_scale[tid] *= (lo ? 0.85f : 1.15f); s_cnt[tid] = 0; atomicAdd(&s_anybad, 1); }
            }
            __syncthreads();
            if (s_anybad == 0) break;
        }

        // ===== exact recompute (4 cand/wave, unroll-2) + select + decode =====
#pragma unroll 1
        for (int q2 = 0; q2 < 4; ++q2) {
            const int r = wu * 4 + q2;
            int n = s_cnt[r]; if (n > CAP) n = CAP;
            const int kq = lane & 15;
            const int cg = lane >> 4;
            const float4 xv = ((const float4*)s_xf32)[r * 16 + kq];
#pragma unroll 2
            for (int s = 0; s < n; s += 4) {
                const int sc = s + cg;
                unsigned j = (sc < n) ? s_buf[r * CAP + sc].y : 0u;
                float4 wv = ((const float4*)We)[(size_t)j * 16 + kq];
                float d = fmaf(wv.x, xv.x, fmaf(wv.y, xv.y, fmaf(wv.z, xv.z, wv.w * xv.w)));
                d += __shfl_xor(d, 1, 64); d += __shfl_xor(d, 2, 64);
                d += __shfl_xor(d, 4, 64); d += __shfl_xor(d, 8, 64);
                if (kq == 0 && sc < n)
                    s_buf[r * CAP + sc].x = __float_as_uint(fmaxf(d + be[j], 0.f));
            }
            // exact u64-key selection (value bits desc, ~idx -> low index wins)
            unsigned long long k0 = 0ull, k1 = 0ull;
            if (lane < n)        { uint2 pp = s_buf[r * CAP + lane];       k0 = ((unsigned long long)pp.x << 32) | (unsigned)(~pp.y); }
            if (lane + 64 < n)   { uint2 pp = s_buf[r * CAP + lane + 64];  k1 = ((unsigned long long)pp.x << 32) | (unsigned)(~pp.y); }
            if (k1 > k0) { unsigned long long t = k0; k0 = k1; k1 = t; }
            unsigned savhi = 0u, savlo = 0u;
#pragma unroll 1
            for (int t = 0; t < KSEL; ++t) {
                unsigned long long m = wave_max_u64(k0);
                if (m == 0ull) break;
                if (lane == t) { savhi = (unsigned)(m >> 32); savlo = (unsigned)m; }
                if (k0 == m) { k0 = k1; k1 = 0ull; }
            }
            // decode: rec = bdv + sum z_t * Wd[idx_t], 4-deep load batching
            float rec = bdv[lane];
#pragma unroll 1
            for (int t = 0; t < KSEL; t += 4) {
                unsigned h0 = __shfl(savhi, t + 0, 64), m0 = __shfl(savlo, t + 0, 64);
                unsigned h1 = __shfl(savhi, t + 1, 64), m1 = __shfl(savlo, t + 1, 64);
                unsigned h2 = __shfl(savhi, t + 2, 64), m2 = __shfl(savlo, t + 2, 64);
                unsigned h3 = __shfl(savhi, t + 3, 64), m3 = __shfl(savlo, t + 3, 64);
                unsigned i0 = h0 ? ~m0 : 0u, i1 = h1 ? ~m1 : 0u;
                unsigned i2 = h2 ? ~m2 : 0u, i3 = h3 ? ~m3 : 0u;
                float w0 = Wd[(size_t)i0 * D64 + lane];
                float w1 = Wd[(size_t)i1 * D64 + lane];
                float w2v = Wd[(size_t)i2 * D64 + lane];
                float w3 = Wd[(size_t)i3 * D64 + lane];
                rec = fmaf(__uint_as_float(h0), w0, rec);
                rec = fmaf(__uint_as_float(h1), w1, rec);
                rec = fmaf(__uint_as_float(h2), w2v, rec);
                rec = fmaf(__uint_as_float(h3), w3, rec);
            }
            if (level == 0) {
                float e = wave_sum_f32(rec * rec);
                if (lane == 0) s_sig[r] = 0.25f * sqrtf(e);   // 2*sigma for level 1
                s_xf32[r * D64 + lane] = rec;                 // recon0 (exact)
                s_ah[r * D64 + 8 * ((lane >> 3) ^ (r & 7)) + (lane & 7)] = f2bf(rec);
            } else {
                float rec0 = s_xf32[r * D64 + lane];
                out[(size_t)(rowbase + r) * D64 + lane] =
                    (1.0f / 1.5f) * rec0 + (0.5f / 1.5f) * rec;
            }
        }
        __syncthreads();   // recon0 buffers visible before level 1
    }
}

extern "C" void kernel_launch(void* const* d_in, const int* in_sizes, int n_in,
                              void* d_out, int out_size, void* d_ws, size_t ws_size,
                              hipStream_t stream) {
    (void)n_in; (void)out_size; (void)ws_size;
    const float* x   = (const float*)d_in[0];
    const float* W1  = (const float*)d_in[1];
    const float* b1  = (const float*)d_in[2];
    const float* Wd1 = (const float*)d_in[3];
    const float* bd1 = (const float*)d_in[4];
    const float* W2  = (const float*)d_in[5];
    const float* b2  = (const float*)d_in[6];
    const float* Wd2 = (const float*)d_in[7];
    const float* bd2 = (const float*)d_in[8];
    unsigned short* wh = (unsigned short*)d_ws;   // 768 KB bf16 swizzled weights

    // prep: (4096+2048) rows * 16 float4 = 98304 threads
    prep_w<<<(HID1 + HID2) * 16 / 256, 256, 0, stream>>>(W1, W2, wh);

    const int batch = in_sizes[0] / D64;     // 16384
    const int grid  = batch / ROWS;          // 512 blocks, 2 per CU

    sae_hier_mfma<<<grid, 512, 0, stream>>>(x, W1, b1, Wd1, bd1, W2, b2, Wd2, bd2,
                                            wh, (float*)d_out);
}

// Round 9
// 207.291 us; speedup vs baseline: 1.2713x; 1.2713x over previous
//
#include <hip/hip_runtime.h>
#include <math.h>

// SAE hierarchical, R9: barrier-free MFMA stream + radix top-k.
// R7/R8 evidence: duration tracks PASS COUNT (24 staged passes x 2 barriers),
// not rows/block -> per-pass fixed cost dominated. R9 removes the pass
// structure: bf16 weights stored LINEAR in d_ws (prep kernel), each wave loads
// its MFMA B-fragments directly global->VGPR from L2 (no LDS B-tile, no
// per-pass barriers; 2 barriers per attempt total). ROWS=16/256-thread blocks
// (LDS ~23KB -> ~4 blocks/CU, 4 independent barrier domains). Top-k: ballot
// binary-search radix select (43 uniform iters) replaces K serial shfl-max
// extractions; compaction via ballot prefix ranks; decode reads LDS directly.
// Numerics: approx pre-acts bf16 MFMA (err ~0.03 << 0.4 threshold margin ->
// candidate set contains true top-k); exact fp32 rescue of all candidates;
// exact u64-key select (value desc, low index tie-break = jax).

#define D64   64
#define ROWS  16
#define CAP   128
#define FTILE 256
#define HID1  4096
#define HID2  2048
#define K1    32
#define K2    16

typedef __attribute__((ext_vector_type(8))) short bf16x8;
typedef __attribute__((ext_vector_type(4))) float f32x4;
typedef unsigned long long u64;

__device__ __forceinline__ unsigned short f2bf(float f) {
    unsigned u = __float_as_uint(f);
    return (unsigned short)((u + 0x7FFFu + ((u >> 16) & 1u)) >> 16);
}

__device__ __forceinline__ float wave_sum_f32(float v) {
#pragma unroll
    for (int off = 32; off > 0; off >>= 1) v += __shfl_xor(v, off, 64);
    return v;
}

// prep: W1|W2 fp32 -> bf16, LINEAR layout. wh[f*64 + k].
__global__ __launch_bounds__(256) void prep_w(const float* __restrict__ W1,
                                              const float* __restrict__ W2,
                                              unsigned short* __restrict__ wh) {
    const int t = blockIdx.x * 256 + threadIdx.x;    // 98304 threads, 1 float4 each
    const int f = t >> 4;
    const float* src = (f < HID1) ? (W1 + (size_t)f * D64)
                                  : (W2 + (size_t)(f - HID1) * D64);
    float4 wv = ((const float4*)src)[t & 15];
    u64 pk = (u64)f2bf(wv.x) | ((u64)f2bf(wv.y) << 16)
           | ((u64)f2bf(wv.z) << 32) | ((u64)f2bf(wv.w) << 48);
    *(u64*)&wh[(size_t)t * 4] = pk;
}

__global__ __launch_bounds__(256) void sae_hier_mfma(
    const float* __restrict__ x,
    const float* __restrict__ W1,  const float* __restrict__ b1,
    const float* __restrict__ Wd1, const float* __restrict__ bd1,
    const float* __restrict__ W2,  const float* __restrict__ b2,
    const float* __restrict__ Wd2, const float* __restrict__ bd2,
    const unsigned short* __restrict__ wh,
    float* __restrict__ out)
{
    __shared__ uint2 s_buf[ROWS * CAP];                       // 16 KB candidates
    __shared__ __align__(16) float s_xf32[ROWS * D64];        // 4 KB exact input
    __shared__ __align__(16) unsigned short s_ah[ROWS * D64]; // 2 KB bf16 A (linear)
    __shared__ float s_sig[ROWS];
    __shared__ float s_thr[ROWS];
    __shared__ float s_scale[ROWS];
    __shared__ int   s_cnt[ROWS];
    __shared__ int   s_act[ROWS];
    __shared__ int   s_anybad;

    const int tid  = threadIdx.x;
    const int lane = tid & 63;
    const int wu   = __builtin_amdgcn_readfirstlane(tid >> 6);  // 4 waves
    const int rowbase = blockIdx.x * ROWS;
    const int g   = lane >> 4;
    const int l15 = lane & 15;

    if (tid < ROWS) { s_cnt[tid] = 0; s_scale[tid] = 1.0f; s_act[tid] = 1; }

    // ---- stage (x - b_dec): fp32 exact + bf16 linear + 2*sigma ----
    {
        const int r = tid >> 4, q = tid & 15;                 // 16 rows x 16 quads
        float4 a = ((const float4*)x)[(size_t)(rowbase + r) * 16 + q];
        float4 b = ((const float4*)bd1)[q];
        float4 v = make_float4(a.x - b.x, a.y - b.y, a.z - b.z, a.w - b.w);
        ((float4*)s_xf32)[r * 16 + q] = v;
        u64 pk = (u64)f2bf(v.x) | ((u64)f2bf(v.y) << 16)
               | ((u64)f2bf(v.z) << 32) | ((u64)f2bf(v.w) << 48);
        *(u64*)&s_ah[(r * 16 + q) * 4] = pk;
        float ss = fmaf(v.x, v.x, fmaf(v.y, v.y, fmaf(v.z, v.z, v.w * v.w)));
        ss += __shfl_xor(ss, 1, 64); ss += __shfl_xor(ss, 2, 64);
        ss += __shfl_xor(ss, 4, 64); ss += __shfl_xor(ss, 8, 64);
        if (q == 0) s_sig[r] = 0.25f * sqrtf(ss);             // 2*sigma = ||.||/4
    }

#define PUSH4(ACC, BIAS, COLG) { \
    float v0 = fmaxf(ACC[0] + (BIAS), 0.f); \
    float v1 = fmaxf(ACC[1] + (BIAS), 0.f); \
    float v2 = fmaxf(ACC[2] + (BIAS), 0.f); \
    float v3 = fmaxf(ACC[3] + (BIAS), 0.f); \
    if (v0 > t0) { int s = atomicAdd(&s_cnt[g*4+0], 1); if (s < CAP) s_buf[(g*4+0)*CAP+s] = make_uint2(__float_as_uint(v0), (unsigned)(COLG)); } \
    if (v1 > t1) { int s = atomicAdd(&s_cnt[g*4+1], 1); if (s < CAP) s_buf[(g*4+1)*CAP+s] = make_uint2(__float_as_uint(v1), (unsigned)(COLG)); } \
    if (v2 > t2) { int s = atomicAdd(&s_cnt[g*4+2], 1); if (s < CAP) s_buf[(g*4+2)*CAP+s] = make_uint2(__float_as_uint(v2), (unsigned)(COLG)); } \
    if (v3 > t3) { int s = atomicAdd(&s_cnt[g*4+3], 1); if (s < CAP) s_buf[(g*4+3)*CAP+s] = make_uint2(__float_as_uint(v3), (unsigned)(COLG)); } }

#pragma unroll 1
    for (int level = 0; level < 2; ++level) {
        const float* We  = level ? W2  : W1;
        const float* be  = level ? b2  : b1;
        const float* Wd  = level ? Wd2 : Wd1;
        const float* bdv = level ? bd2 : bd1;
        const unsigned short* whL = wh + (level ? (size_t)HID1 * D64 : 0);
        const int KSEL   = level ? K2 : K1;
        const int NPASS  = (level ? HID2 : HID1) / FTILE;

        __syncthreads();

        // ======== barrier-free approx GEMM + threshold push (with retry) ========
#pragma unroll 1
        for (int attempt = 0; attempt < 8; ++attempt) {
            if (tid < ROWS) s_thr[tid] = s_act[tid] ? s_sig[tid] * s_scale[tid] : 3.4e38f;
            __syncthreads();
            // A fragments: row = l15, k-halfwords 8g..8g+7 (lo) / 32+8g (hi)
            bf16x8 a0 = *(const bf16x8*)&s_ah[l15 * D64 + 8 * g];
            bf16x8 a1 = *(const bf16x8*)&s_ah[l15 * D64 + 32 + 8 * g];
            const float t0 = s_thr[g * 4 + 0], t1 = s_thr[g * 4 + 1];
            const float t2 = s_thr[g * 4 + 2], t3 = s_thr[g * 4 + 3];

#pragma unroll 1
            for (int p = 0; p < NPASS; ++p) {
                const int fbase = p * FTILE + wu * 64 + l15;
                const unsigned short* wb = whL + (size_t)fbase * D64;
                const float* bb = be + fbase;
                {   // subs 0,1
                    bf16x8 b00 = *(const bf16x8*)&wb[8 * g];
                    bf16x8 b01 = *(const bf16x8*)&wb[8 * g + 32];
                    bf16x8 b10 = *(const bf16x8*)&wb[8 * g + 1024];
                    bf16x8 b11 = *(const bf16x8*)&wb[8 * g + 1056];
                    float bias0 = bb[0], bias1 = bb[16];
                    f32x4 acc0 = {0.f, 0.f, 0.f, 0.f}, acc1 = {0.f, 0.f, 0.f, 0.f};
                    acc0 = __builtin_amdgcn_mfma_f32_16x16x32_bf16(a0, b00, acc0, 0, 0, 0);
                    acc0 = __builtin_amdgcn_mfma_f32_16x16x32_bf16(a1, b01, acc0, 0, 0, 0);
                    acc1 = __builtin_amdgcn_mfma_f32_16x16x32_bf16(a0, b10, acc1, 0, 0, 0);
                    acc1 = __builtin_amdgcn_mfma_f32_16x16x32_bf16(a1, b11, acc1, 0, 0, 0);
                    PUSH4(acc0, bias0, fbase)
                    PUSH4(acc1, bias1, fbase + 16)
                }
                {   // subs 2,3
                    bf16x8 b20 = *(const bf16x8*)&wb[8 * g + 2048];
                    bf16x8 b21 = *(const bf16x8*)&wb[8 * g + 2080];
                    bf16x8 b30 = *(const bf16x8*)&wb[8 * g + 3072];
                    bf16x8 b31 = *(const bf16x8*)&wb[8 * g + 3104];
                    float bias2 = bb[32], bias3 = bb[48];
                    f32x4 acc2 = {0.f, 0.f, 0.f, 0.f}, acc3 = {0.f, 0.f, 0.f, 0.f};
                    acc2 = __builtin_amdgcn_mfma_f32_16x16x32_bf16(a0, b20, acc2, 0, 0, 0);
                    acc2 = __builtin_amdgcn_mfma_f32_16x16x32_bf16(a1, b21, acc2, 0, 0, 0);
                    acc3 = __builtin_amdgcn_mfma_f32_16x16x32_bf16(a0, b30, acc3, 0, 0, 0);
                    acc3 = __builtin_amdgcn_mfma_f32_16x16x32_bf16(a1, b31, acc3, 0, 0, 0);
                    PUSH4(acc2, bias2, fbase + 32)
                    PUSH4(acc3, bias3, fbase + 48)
                }
            }
            __syncthreads();
            if (tid == 0) s_anybad = 0;
            __syncthreads();
            if (tid < ROWS) {
                int c = s_cnt[tid];
                bool lo = (c < KSEL), hi = (c > CAP);
                bool bad = (lo || hi) && (attempt < 7);
                s_act[tid] = bad ? 1 : 0;
                if (bad) { s_scale[tid] *= (lo ? 0.85f : 1.15f); s_cnt[tid] = 0; atomicAdd(&s_anybad, 1); }
            }
            __syncthreads();
            if (s_anybad == 0) break;
        }

        // ==== exact rescue + radix top-k (ballot binary search) + decode ====
#pragma unroll 1
        for (int q2 = 0; q2 < 4; ++q2) {
            const int r = wu * 4 + q2;
            int n = s_cnt[r]; if (n > CAP) n = CAP;
            const int kq = lane & 15;
            const int cg = lane >> 4;
            const float4 xv = ((const float4*)s_xf32)[r * 16 + kq];
#pragma unroll 2
            for (int s = 0; s < n; s += 4) {
                const int sc = s + cg;
                unsigned j = (sc < n) ? s_buf[r * CAP + sc].y : 0u;
                float4 wv = ((const float4*)We)[(size_t)j * 16 + kq];
                float d = fmaf(wv.x, xv.x, fmaf(wv.y, xv.y, fmaf(wv.z, xv.z, wv.w * xv.w)));
                d += __shfl_xor(d, 1, 64); d += __shfl_xor(d, 2, 64);
                d += __shfl_xor(d, 4, 64); d += __shfl_xor(d, 8, 64);
                if (kq == 0 && sc < n)
                    s_buf[r * CAP + sc].x = __float_as_uint(fmaxf(d + be[j], 0.f));
            }
            // keys: (exact valbits << 32) | ~idx  (distinct; low index wins ties)
            u64 k0 = 0ull, k1 = 0ull;
            if (lane < n)      { uint2 pp = s_buf[r * CAP + lane];      k0 = ((u64)pp.x << 32) | (unsigned)(~pp.y); }
            if (lane + 64 < n) { uint2 pp = s_buf[r * CAP + lane + 64]; k1 = ((u64)pp.x << 32) | (unsigned)(~pp.y); }
            // radix select: T = KSEL-th largest key. val bits 62..32, then the
            // always-1 band (idx < 4096 -> ~idx bits 12..31 set), then 11..0.
            u64 T = 0ull;
#pragma unroll 1
            for (int b = 62; b >= 32; --b) {
                u64 cand = T | (1ull << b);
                int c = __popcll(__ballot(k0 >= cand)) + __popcll(__ballot(k1 >= cand));
                if (c >= KSEL) T = cand;
            }
            T |= 0xFFFFF000ull;
#pragma unroll 1
            for (int b = 11; b >= 0; --b) {
                u64 cand = T | (1ull << b);
                int c = __popcll(__ballot(k0 >= cand)) + __popcll(__ballot(k1 >= cand));
                if (c >= KSEL) T = cand;
            }
            // compact the exactly-KSEL selected keys into slots [0, KSEL)
            bool f0 = (k0 >= T), f1 = (k1 >= T);
            u64 m0 = __ballot(f0), m1 = __ballot(f1);
            u64 below = (1ull << lane) - 1ull;
            int r0 = __popcll(m0 & below);
            int r1 = __popcll(m0) + __popcll(m1 & below);
            if (f0) s_buf[r * CAP + r0] = make_uint2((unsigned)(k0 >> 32), ~(unsigned)k0);
            if (f1) s_buf[r * CAP + r1] = make_uint2((unsigned)(k1 >> 32), ~(unsigned)k1);
            // decode: rec = bdv + sum z_t * Wd[idx_t] (LDS-broadcast reads)
            float rec = bdv[lane];
#pragma unroll 1
            for (int t = 0; t < KSEL; t += 4) {
                uint2 e0 = s_buf[r * CAP + t + 0];
                uint2 e1 = s_buf[r * CAP + t + 1];
                uint2 e2 = s_buf[r * CAP + t + 2];
                uint2 e3 = s_buf[r * CAP + t + 3];
                float w0 = Wd[(size_t)e0.y * D64 + lane];
                float w1 = Wd[(size_t)e1.y * D64 + lane];
                float w2 = Wd[(size_t)e2.y * D64 + lane];
                float w3 = Wd[(size_t)e3.y * D64 + lane];
                rec = fmaf(__uint_as_float(e0.x), w0, rec);
                rec = fmaf(__uint_as_float(e1.x), w1, rec);
                rec = fmaf(__uint_as_float(e2.x), w2, rec);
                rec = fmaf(__uint_as_float(e3.x), w3, rec);
            }
            if (level == 0) {
                float e = wave_sum_f32(rec * rec);
                if (lane == 0) s_sig[r] = 0.25f * sqrtf(e);   // 2*sigma for level 1
                s_xf32[r * D64 + lane] = rec;                 // exact recon0
                s_ah[r * D64 + lane] = f2bf(rec);             // bf16 A for level 1
                if (lane < ROWS && q2 == 0 && wu == 0) { }    // (no-op)
            } else {
                float rec0 = s_xf32[r * D64 + lane];
                out[(size_t)(rowbase + r) * D64 + lane] =
                    (1.0f / 1.5f) * rec0 + (0.5f / 1.5f) * rec;
            }
        }
        if (level == 0) {
            __syncthreads();
            if (tid < ROWS) { s_cnt[tid] = 0; s_scale[tid] = 1.0f; s_act[tid] = 1; }
        }
    }
}

extern "C" void kernel_launch(void* const* d_in, const int* in_sizes, int n_in,
                              void* d_out, int out_size, void* d_ws, size_t ws_size,
                              hipStream_t stream) {
    (void)n_in; (void)out_size; (void)ws_size;
    const float* x   = (const float*)d_in[0];
    const float* W1  = (const float*)d_in[1];
    const float* b1  = (const float*)d_in[2];
    const float* Wd1 = (const float*)d_in[3];
    const float* bd1 = (const float*)d_in[4];
    const float* W2  = (const float*)d_in[5];
    const float* b2  = (const float*)d_in[6];
    const float* Wd2 = (const float*)d_in[7];
    const float* bd2 = (const float*)d_in[8];
    unsigned short* wh = (unsigned short*)d_ws;   // 768 KB bf16 linear weights

    prep_w<<<(HID1 + HID2) * 16 / 256, 256, 0, stream>>>(W1, W2, wh);

    const int batch = in_sizes[0] / D64;     // 16384
    const int grid  = batch / ROWS;          // 1024 blocks

    sae_hier_mfma<<<grid, 256, 0, stream>>>(x, W1, b1, Wd1, bd1, W2, b2, Wd2, bd2,
                                            wh, (float*)d_out);
}